// Round 15
// baseline (366.429 us; speedup 1.0000x reference)
//
#include <hip/hip_runtime.h>
#include <hip/hip_bf16.h>

#define B_ 4
#define S_ 2048
#define D_ 512
#define H_ 8
#define DH_ 64
#define HD_ 512
#define M_ 8192
#define QKVN 1536
#define QKN 1024
#define LOG2E 1.4426950408889634f

typedef __attribute__((ext_vector_type(8))) short bf16x8;
typedef __attribute__((ext_vector_type(4))) float f32x4;
typedef unsigned short u16;
typedef unsigned int u32;

__device__ inline u16 f2bf(float f) {
    __hip_bfloat16 h = __float2bfloat16(f);
    return *reinterpret_cast<u16*>(&h);
}
__device__ inline float bf2f(u16 u) {
    union { u32 i; float f; } v; v.i = (u32)u << 16; return v.f;
}

__device__ inline void async_cp16(const void* g, void* l) {
    __builtin_amdgcn_global_load_lds(
        (const __attribute__((address_space(1))) unsigned int*)g,
        (__attribute__((address_space(3))) unsigned int*)l, 16, 0, 0);
}

// ---------------------------------------------------------------------------
// Combined prep: z<3 -> transpose Wq/Wk/Wv (512x512 f32) into WqkvT bf16;
// z==3 -> transpose Wo (512x64) into WoT; z==4 -> cast x f32->bf16.
// Grid (64, 8, 5).
// ---------------------------------------------------------------------------
__global__ __launch_bounds__(256) void prep_all(
    const float* __restrict__ x, const float* __restrict__ Wq,
    const float* __restrict__ Wk, const float* __restrict__ Wv,
    const float* __restrict__ Wo, u16* __restrict__ xb,
    u16* __restrict__ WqkvT, u16* __restrict__ WoT)
{
    const int z = blockIdx.z;
    const int tid = threadIdx.x;

    if (z == 4) {            // ---- cast x -> bf16, 4 chunks per thread ----
        const int id = blockIdx.y * 64 + blockIdx.x;     // 0..511
#pragma unroll
        for (int it = 0; it < 4; ++it) {
            int i = it * 131072 + id * 256 + tid;        // n8 = 524288
            float4 a = *reinterpret_cast<const float4*>(&x[(size_t)i * 8]);
            float4 b = *reinterpret_cast<const float4*>(&x[(size_t)i * 8 + 4]);
            bf16x8 o;
            o[0] = f2bf(a.x); o[1] = f2bf(a.y); o[2] = f2bf(a.z); o[3] = f2bf(a.w);
            o[4] = f2bf(b.x); o[5] = f2bf(b.y); o[6] = f2bf(b.z); o[7] = f2bf(b.w);
            *reinterpret_cast<bf16x8*>(&xb[(size_t)i * 8]) = o;
        }
        return;
    }

    const float* src; u16* dst; int R, C;
    if (z < 3) { if (blockIdx.x >= 8) return;
                 src = (z == 0) ? Wq : (z == 1) ? Wk : Wv;
                 dst = WqkvT + (size_t)z * 512 * 512; R = 512; C = 512; }
    else       { if (blockIdx.x) return; src = Wo; dst = WoT; R = 512; C = 64; }

    __shared__ u16 T[64][65];
    const int c0 = blockIdx.x * 64, r0 = blockIdx.y * 64;
#pragma unroll
    for (int i = 0; i < 4; ++i) {
        int idx = i * 256 + tid;
        int r = idx >> 4, q4 = (idx & 15) << 2;
        float4 vv = *reinterpret_cast<const float4*>(&src[(size_t)(r0 + r) * C + c0 + q4]);
        T[r][q4 + 0] = f2bf(vv.x); T[r][q4 + 1] = f2bf(vv.y);
        T[r][q4 + 2] = f2bf(vv.z); T[r][q4 + 3] = f2bf(vv.w);
    }
    __syncthreads();
#pragma unroll
    for (int i = 0; i < 2; ++i) {
        int idx = i * 256 + tid;
        int cc = idx >> 3, jj = idx & 7;
        bf16x8 o;
#pragma unroll
        for (int e = 0; e < 8; ++e) o[e] = (short)T[jj * 8 + e][cc];
        *reinterpret_cast<bf16x8*>(&dst[(size_t)(c0 + cc) * R + r0 + jj * 8]) = o;
    }
}

// ---------------------------------------------------------------------------
// Fused QKV GEMM: [M,512] @ [1536,512]^T. Q/K cols -> qk[M][1024] (q scaled
// by 0.125*log2e); V cols -> v3 re-blocked fragment layout:
//   v3[bh][t 32][n 4][ks 2][l4 4][dd 16][kvi 8]
// Tile 128x128, BK=64, 4 waves. Flat grid 768 with bijective XCD swizzle.
// ---------------------------------------------------------------------------
__global__ __launch_bounds__(256) void gemm_qkv(
    const u16* __restrict__ A, const u16* __restrict__ BT,
    const float* __restrict__ bq, const float* __restrict__ bk,
    const float* __restrict__ bv, u16* __restrict__ qk,
    u16* __restrict__ v3, float qscale)
{
    __shared__ __align__(16) u16 As[128 * 64];
    __shared__ __align__(16) u16 Bs[128 * 64];
    const int tid = threadIdx.x, lane = tid & 63, w = tid >> 6;
    const int l15 = lane & 15, l4 = lane >> 4;

    const int bidf = blockIdx.x;
    const int xcd = bidf & 7, pos = bidf >> 3;
    const int swz = xcd * 96 + pos;
    const int by = swz / 12, bx = swz - by * 12;
    const int tm = by * 128, tn = bx * 128;
    const int wm = (w >> 1) * 64, wn = (w & 1) * 64;

    f32x4 acc[4][4] = {};

    for (int k0 = 0; k0 < 512; k0 += 64) {
#pragma unroll
        for (int i = 0; i < 4; ++i) {
            int call = w * 4 + i;
            int c = call * 64 + lane;
            int r = c >> 3, j = c & 7;
            async_cp16(A + (size_t)(tm + r) * 512 + k0 + ((j ^ (r & 7)) << 3),
                       &As[call * 512]);
            async_cp16(BT + (size_t)(tn + r) * 512 + k0 + ((j ^ (r & 7)) << 3),
                       &Bs[call * 512]);
        }
        __syncthreads();
#pragma unroll
        for (int ks = 0; ks < 2; ++ks) {
            bf16x8 af[4], bf[4];
#pragma unroll
            for (int mf = 0; mf < 4; ++mf) {
                int r = wm + mf * 16 + l15;
                int j = ks * 4 + l4;
                af[mf] = *reinterpret_cast<const bf16x8*>(&As[(r * 8 + (j ^ (r & 7))) * 8]);
            }
#pragma unroll
            for (int nf = 0; nf < 4; ++nf) {
                int r = wn + nf * 16 + l15;
                int j = ks * 4 + l4;
                bf[nf] = *reinterpret_cast<const bf16x8*>(&Bs[(r * 8 + (j ^ (r & 7))) * 8]);
            }
#pragma unroll
            for (int mf = 0; mf < 4; ++mf)
#pragma unroll
                for (int nf = 0; nf < 4; ++nf)
                    acc[mf][nf] = __builtin_amdgcn_mfma_f32_16x16x32_bf16(
                        af[mf], bf[nf], acc[mf][nf], 0, 0, 0);
        }
        __syncthreads();
    }
    // epilogue: C/D col=lane&15, row=(lane>>4)*4+reg
#pragma unroll
    for (int nf = 0; nf < 4; ++nf) {
        const int col = tn + wn + nf * 16 + l15;
        if (col < QKN) {
            const float bias_v = (col < 512) ? bq[col] : bk[col - 512];
            const float scl = (col < 512) ? qscale : 1.0f;
#pragma unroll
            for (int mf = 0; mf < 4; ++mf)
#pragma unroll
                for (int r = 0; r < 4; ++r) {
                    int row = tm + wm + mf * 16 + l4 * 4 + r;
                    qk[(size_t)row * QKN + col] = f2bf((acc[mf][nf][r] + bias_v) * scl);
                }
        } else {
            const int dcol = col - QKN;                  // 0..511
            const float bias_v = bv[dcol];
            const int hh = dcol >> 6, d64 = dcol & 63;
            const int n = d64 >> 4, dd = d64 & 15;
#pragma unroll
            for (int mf = 0; mf < 4; ++mf) {
                int row0 = tm + wm + mf * 16 + l4 * 4;
                int b = row0 >> 11, s = row0 & 2047;
                int t = s >> 6, s6 = s & 63;
                int ks = s6 >> 5, l4i = (s6 >> 3) & 3, kvi = s6 & 7;
                ushort4 pk;
                pk.x = f2bf(acc[mf][nf][0] + bias_v);
                pk.y = f2bf(acc[mf][nf][1] + bias_v);
                pk.z = f2bf(acc[mf][nf][2] + bias_v);
                pk.w = f2bf(acc[mf][nf][3] + bias_v);
                size_t idx = (((((size_t)(b * 8 + hh) * 32 + t) * 4 + n) * 2 + ks) * 4
                              + l4i) * 128 + dd * 8 + kvi;
                *reinterpret_cast<ushort4*>(&v3[idx]) = pk;
            }
        }
    }
}

// ---------------------------------------------------------------------------
// Flash attention v15 = v13 inner structure, kv-SPLIT x2 for occupancy:
// grid 2048 (8 blocks/CU, ~32 waves/CU), each block does 16 kv tiles
// (half = bid-decoded), writes UNNORMALIZED O (bf16) + l (f32) partials.
// K pi-permuted staging (16KB LDS dbuf), swapped QK^T, register P,
// ones-MFMA row sums, V from re-blocked v3 in L2.
// ---------------------------------------------------------------------------
__global__ __launch_bounds__(256, 8) void flash_mfma(
    const u16* __restrict__ qk, const u16* __restrict__ v3,
    const float* __restrict__ pw_ptr, u16* __restrict__ opart,
    float* __restrict__ lpart)
{
    __shared__ __align__(16) u16 Kb[2][4096];   // [64 rho][64 dh], chunk-swz

    const int tid = threadIdx.x, lane = tid & 63, w = tid >> 6;
    const int l15 = lane & 15, l4 = lane >> 4;
    const int bid = blockIdx.x;
    const int x = bid & 7, g = bid >> 3;          // g in [0,256)
    const int bh = x * 4 + (g >> 6);              // XCD x owns bh 4x..4x+3
    const int rem = g & 63, qt = rem >> 1, half = rem & 1;
    const int h = bh & 7, b = bh >> 3;
    const float pwl = pw_ptr[0] * LOG2E;

    const u16* qbase = qk + (size_t)b * S_ * QKN + h * 64;
    const u16* kbase = qbase + 512;
    const u16* vbase = v3 + (size_t)bh * 32 * 4 * 2 * 512 + l4 * 128 + l15 * 8;

    const int qrow0 = qt * 64 + w * 16;   // wave's first q row
    bf16x8 qb[2];
#pragma unroll
    for (int ks2 = 0; ks2 < 2; ++ks2)
        qb[ks2] = *reinterpret_cast<const bf16x8*>(
            &qbase[(size_t)(qrow0 + l15) * QKN + ks2 * 32 + l4 * 8]);

    const bf16x8 ones = {(short)0x3F80, (short)0x3F80, (short)0x3F80, (short)0x3F80,
                         (short)0x3F80, (short)0x3F80, (short)0x3F80, (short)0x3F80};

    f32x4 accv[4] = {};
    f32x4 accl = {};
    const int t0 = half * 16;

#define STAGE(buf, jj) do {                                                        \
    _Pragma("unroll")                                                              \
    for (int i_ = 0; i_ < 2; ++i_) {                                               \
        int call_ = w * 2 + i_;                                                    \
        int c_ = call_ * 64 + lane;                                                \
        int rho_ = c_ >> 3, j_ = c_ & 7;                                           \
        int pi_ = (rho_ & 32) | ((rho_ & 12) << 1) | ((rho_ & 16) >> 2)            \
                | (rho_ & 3);                                                      \
        async_cp16(kbase + (size_t)((jj) + pi_) * QKN + ((j_ ^ (rho_ & 7)) << 3),  \
                   &Kb[buf][call_ * 512]);                                         \
    } } while (0)

    STAGE(0, t0 << 6);
    __syncthreads();
    int cur = 0;

    for (int ti = 0; ti < 16; ++ti) {
        const int t = t0 + ti;
        const int j0 = t << 6;
        const u16* vt = vbase + (size_t)t * 4096;

        // ---- V B-frags n=0,1 early (contiguous 1KB loads from L2) ----
        bf16x8 vb01[2][2];
#pragma unroll
        for (int n = 0; n < 2; ++n)
#pragma unroll
            for (int ks = 0; ks < 2; ++ks)
                vb01[n][ks] = *reinterpret_cast<const bf16x8*>(
                    vt + (n * 2 + ks) * 512);

        if (ti < 15) STAGE(cur ^ 1, (t + 1) << 6);

        // ---- swapped QK^T: S^T[rho][q], A = K(permuted) LDS, B = Q regs ----
        f32x4 s[4] = {};
        __builtin_amdgcn_s_setprio(1);
#pragma unroll
        for (int c = 0; c < 4; ++c)
#pragma unroll
            for (int ks2 = 0; ks2 < 2; ++ks2) {
                const int rr = c * 16 + l15;
                const int sl = ks2 * 4 + l4;
                bf16x8 ka = *reinterpret_cast<const bf16x8*>(
                    &Kb[cur][(rr * 8 + (sl ^ (rr & 7))) * 8]);
                s[c] = __builtin_amdgcn_mfma_f32_16x16x32_bf16(ka, qb[ks2], s[c], 0, 0, 0);
            }
        __builtin_amdgcn_s_setprio(0);

        // ---- V B-frags n=2,3 ----
        bf16x8 vb23[2][2];
#pragma unroll
        for (int n = 0; n < 2; ++n)
#pragma unroll
            for (int ks = 0; ks < 2; ++ks)
                vb23[n][ks] = *reinterpret_cast<const bf16x8*>(
                    vt + ((n + 2) * 2 + ks) * 512);

        // ---- diagonal prior: kv = (c>>1)*32 + l4*8 + (c&1)*4 + r ----
        if (t == qt) {
#pragma unroll
            for (int c = 0; c < 4; ++c)
#pragma unroll
                for (int r = 0; r < 4; ++r) {
                    int kv = (c >> 1) * 32 + l4 * 8 + (c & 1) * 4 + r;
                    if (j0 + kv == qrow0 + l15) s[c][r] += pwl;
                }
        }

        // ---- P = 2^s -> PV A-fragments (pure registers) ----
        bf16x8 pa[2];
#pragma unroll
        for (int ks = 0; ks < 2; ++ks)
#pragma unroll
            for (int d2 = 0; d2 < 2; ++d2)
#pragma unroll
                for (int r = 0; r < 4; ++r)
                    pa[ks][d2 * 4 + r] = (short)f2bf(exp2f(s[ks * 2 + d2][r]));

        // ---- PV + ones-row-sum ----
        __builtin_amdgcn_s_setprio(1);
        accl = __builtin_amdgcn_mfma_f32_16x16x32_bf16(pa[0], ones, accl, 0, 0, 0);
        accl = __builtin_amdgcn_mfma_f32_16x16x32_bf16(pa[1], ones, accl, 0, 0, 0);
#pragma unroll
        for (int n = 0; n < 2; ++n)
#pragma unroll
            for (int ks = 0; ks < 2; ++ks)
                accv[n] = __builtin_amdgcn_mfma_f32_16x16x32_bf16(
                    pa[ks], vb01[n][ks], accv[n], 0, 0, 0);
#pragma unroll
        for (int n = 0; n < 2; ++n)
#pragma unroll
            for (int ks = 0; ks < 2; ++ks)
                accv[n + 2] = __builtin_amdgcn_mfma_f32_16x16x32_bf16(
                    pa[ks], vb23[n][ks], accv[n + 2], 0, 0, 0);
        __builtin_amdgcn_s_setprio(0);

        __syncthreads();
        cur ^= 1;
    }
#undef STAGE

    // ---- epilogue: write unnormalized partials ----
    const size_t cell = (size_t)(bh * 32 + qt) * 2 + half;
#pragma unroll
    for (int r = 0; r < 4; ++r) {
        const int row6 = w * 16 + l4 * 4 + r;
#pragma unroll
        for (int nf = 0; nf < 4; ++nf)
            opart[cell * 4096 + (size_t)row6 * 64 + nf * 16 + l15] =
                f2bf(accv[nf][r]);
        if (l15 == 0) lpart[cell * 64 + row6] = accl[r];
    }
}

// ---------------------------------------------------------------------------
// Combine: att = (O0 + O1) / (l0 + l1).  Grid 1024 (bh*32+qt), 256 thr.
// Thread: row = tid>>2, 16 cols at (tid&3)*16.
// ---------------------------------------------------------------------------
__global__ __launch_bounds__(256) void combine(
    const u16* __restrict__ opart, const float* __restrict__ lpart,
    u16* __restrict__ att)
{
    const int cp = blockIdx.x;            // bh*32 + qt
    const int bh = cp >> 5, qt = cp & 31;
    const int h = bh & 7, b = bh >> 3;
    const int tid = threadIdx.x;
    const int row = tid >> 2, cg = tid & 3;

    const float inv = 1.0f / (lpart[(size_t)cp * 128 + row] +
                              lpart[(size_t)cp * 128 + 64 + row]);
    const u16* p0 = opart + (size_t)cp * 8192 + (size_t)row * 64 + cg * 16;
    const u16* p1 = p0 + 4096;

    u16* dst = att + ((size_t)(b * S_ + qt * 64 + row)) * HD_ + h * 64 + cg * 16;
#pragma unroll
    for (int hchunk = 0; hchunk < 2; ++hchunk) {
        bf16x8 a = *reinterpret_cast<const bf16x8*>(p0 + hchunk * 8);
        bf16x8 c = *reinterpret_cast<const bf16x8*>(p1 + hchunk * 8);
        bf16x8 o;
#pragma unroll
        for (int e = 0; e < 8; ++e)
            o[e] = (short)f2bf((bf2f((u16)a[e]) + bf2f((u16)c[e])) * inv);
        *reinterpret_cast<bf16x8*>(dst + hchunk * 8) = o;
    }
}

// ---------------------------------------------------------------------------
// Output projection v2: out[M,64] = att[M,512] @ WoT[64,512]^T + bo.
// 32 rows/block, 4 waves: (row-group w&1) x (K-half w>>1); f32 partials
// reduced through LDS. Grid 256.
// ---------------------------------------------------------------------------
__global__ __launch_bounds__(256) void out_proj(
    const u16* __restrict__ att, const u16* __restrict__ WoT,
    const float* __restrict__ bo, float* __restrict__ out)
{
    __shared__ float red[32][65];
    const int tid = threadIdx.x, lane = tid & 63, w = tid >> 6;
    const int l15 = lane & 15, l4 = lane >> 4;
    const int row0 = blockIdx.x * 32;
    const int rsub = (w & 1) * 16, kh = w >> 1;

    f32x4 acc[4] = {};
#pragma unroll
    for (int ks = 0; ks < 8; ++ks) {
        bf16x8 a = *reinterpret_cast<const bf16x8*>(
            &att[(size_t)(row0 + rsub + l15) * 512 + (kh * 8 + ks) * 32 + l4 * 8]);
#pragma unroll
        for (int nf = 0; nf < 4; ++nf) {
            bf16x8 bb = *reinterpret_cast<const bf16x8*>(
                &WoT[(size_t)(nf * 16 + l15) * 512 + (kh * 8 + ks) * 32 + l4 * 8]);
            acc[nf] = __builtin_amdgcn_mfma_f32_16x16x32_bf16(a, bb, acc[nf], 0, 0, 0);
        }
    }
    if (kh == 1) {
#pragma unroll
        for (int nf = 0; nf < 4; ++nf)
#pragma unroll
            for (int r = 0; r < 4; ++r)
                red[rsub + l4 * 4 + r][nf * 16 + l15] = acc[nf][r];
    }
    __syncthreads();
    if (kh == 0) {
#pragma unroll
        for (int nf = 0; nf < 4; ++nf) {
            int n = nf * 16 + l15;
            float bias_v = bo[n];
#pragma unroll
            for (int r = 0; r < 4; ++r)
                out[(size_t)(row0 + rsub + l4 * 4 + r) * 64 + n] =
                    acc[nf][r] + red[rsub + l4 * 4 + r][n] + bias_v;
        }
    }
}

// ---------------------------------------------------------------------------
extern "C" void kernel_launch(void* const* d_in, const int* in_sizes, int n_in,
                              void* d_out, int out_size, void* d_ws, size_t ws_size,
                              hipStream_t stream)
{
    const float* x  = (const float*)d_in[0];
    const float* Wq = (const float*)d_in[2];
    const float* bq = (const float*)d_in[3];
    const float* Wk = (const float*)d_in[4];
    const float* bk = (const float*)d_in[5];
    const float* Wv = (const float*)d_in[6];
    const float* bv = (const float*)d_in[7];
    const float* Wo = (const float*)d_in[8];
    const float* bo = (const float*)d_in[9];
    const float* pw = (const float*)d_in[10];

    u16* ws = (u16*)d_ws;
    size_t o = 0;
    u16* xb    = ws + o; o += (size_t)M_ * D_;           // 8 MB
    u16* WqkvT = ws + o; o += (size_t)QKVN * D_;         // 1.5 MB
    u16* WoT   = ws + o; o += (size_t)DH_ * HD_;
    u16* qkb   = ws + o; o += (size_t)M_ * QKN;          // 16 MB
    u16* v3b   = ws + o; o += (size_t)M_ * HD_;          // 8 MB
    u16* att   = ws + o; o += (size_t)M_ * HD_;          // 8 MB
    u16* opart = ws + o; o += (size_t)2048 * 4096;       // 16 MB (bf16)
    float* lprt = (float*)(ws + o); o += (size_t)2048 * 64 * 2;  // 512 KB

    dim3 blk(256);
    prep_all<<<dim3(64, 8, 5), blk, 0, stream>>>(x, Wq, Wk, Wv, Wo, xb, WqkvT, WoT);

    gemm_qkv<<<dim3(768), blk, 0, stream>>>(
        xb, WqkvT, bq, bk, bv, qkb, v3b, 0.125f * LOG2E);

    flash_mfma<<<dim3(2048), blk, 0, stream>>>(qkb, v3b, pw, opart, lprt);

    combine<<<dim3(1024), blk, 0, stream>>>(opart, lprt, att);

    out_proj<<<dim3(256), blk, 0, stream>>>(att, WoT, bo, (float*)d_out);
}

// Round 16
// 213.771 us; speedup vs baseline: 1.7141x; 1.7141x over previous
//
#include <hip/hip_runtime.h>
#include <hip/hip_bf16.h>

#define B_ 4
#define S_ 2048
#define D_ 512
#define H_ 8
#define DH_ 64
#define HD_ 512
#define M_ 8192
#define QKVN 1536
#define QKN 1024
#define LOG2E 1.4426950408889634f

typedef __attribute__((ext_vector_type(8))) short bf16x8;
typedef __attribute__((ext_vector_type(4))) float f32x4;
typedef unsigned short u16;
typedef unsigned int u32;

__device__ inline u16 f2bf(float f) {
    __hip_bfloat16 h = __float2bfloat16(f);
    return *reinterpret_cast<u16*>(&h);
}
__device__ inline float bf2f(u16 u) {
    union { u32 i; float f; } v; v.i = (u32)u << 16; return v.f;
}

__device__ inline void async_cp16(const void* g, void* l) {
    __builtin_amdgcn_global_load_lds(
        (const __attribute__((address_space(1))) unsigned int*)g,
        (__attribute__((address_space(3))) unsigned int*)l, 16, 0, 0);
}

// ---------------------------------------------------------------------------
// Combined prep: z<3 -> transpose Wq/Wk/Wv (512x512 f32) into WqkvT bf16;
// z==3 -> transpose Wo (512x64) into WoT; z==4 -> cast x f32->bf16.
// Grid (64, 8, 5).
// ---------------------------------------------------------------------------
__global__ __launch_bounds__(256) void prep_all(
    const float* __restrict__ x, const float* __restrict__ Wq,
    const float* __restrict__ Wk, const float* __restrict__ Wv,
    const float* __restrict__ Wo, u16* __restrict__ xb,
    u16* __restrict__ WqkvT, u16* __restrict__ WoT)
{
    const int z = blockIdx.z;
    const int tid = threadIdx.x;

    if (z == 4) {            // ---- cast x -> bf16, 4 chunks per thread ----
        const int id = blockIdx.y * 64 + blockIdx.x;     // 0..511
#pragma unroll
        for (int it = 0; it < 4; ++it) {
            int i = it * 131072 + id * 256 + tid;        // n8 = 524288
            float4 a = *reinterpret_cast<const float4*>(&x[(size_t)i * 8]);
            float4 b = *reinterpret_cast<const float4*>(&x[(size_t)i * 8 + 4]);
            bf16x8 o;
            o[0] = f2bf(a.x); o[1] = f2bf(a.y); o[2] = f2bf(a.z); o[3] = f2bf(a.w);
            o[4] = f2bf(b.x); o[5] = f2bf(b.y); o[6] = f2bf(b.z); o[7] = f2bf(b.w);
            *reinterpret_cast<bf16x8*>(&xb[(size_t)i * 8]) = o;
        }
        return;
    }

    const float* src; u16* dst; int R, C;
    if (z < 3) { if (blockIdx.x >= 8) return;
                 src = (z == 0) ? Wq : (z == 1) ? Wk : Wv;
                 dst = WqkvT + (size_t)z * 512 * 512; R = 512; C = 512; }
    else       { if (blockIdx.x) return; src = Wo; dst = WoT; R = 512; C = 64; }

    __shared__ u16 T[64][65];
    const int c0 = blockIdx.x * 64, r0 = blockIdx.y * 64;
#pragma unroll
    for (int i = 0; i < 4; ++i) {
        int idx = i * 256 + tid;
        int r = idx >> 4, q4 = (idx & 15) << 2;
        float4 vv = *reinterpret_cast<const float4*>(&src[(size_t)(r0 + r) * C + c0 + q4]);
        T[r][q4 + 0] = f2bf(vv.x); T[r][q4 + 1] = f2bf(vv.y);
        T[r][q4 + 2] = f2bf(vv.z); T[r][q4 + 3] = f2bf(vv.w);
    }
    __syncthreads();
#pragma unroll
    for (int i = 0; i < 2; ++i) {
        int idx = i * 256 + tid;
        int cc = idx >> 3, jj = idx & 7;
        bf16x8 o;
#pragma unroll
        for (int e = 0; e < 8; ++e) o[e] = (short)T[jj * 8 + e][cc];
        *reinterpret_cast<bf16x8*>(&dst[(size_t)(c0 + cc) * R + r0 + jj * 8]) = o;
    }
}

// ---------------------------------------------------------------------------
// Fused QKV GEMM: [M,512] @ [1536,512]^T. Q/K cols -> qk[M][1024] (q scaled
// by 0.125*log2e); V cols -> v3 re-blocked fragment layout:
//   v3[bh][t 32][n 4][ks 2][l4 4][dd 16][kvi 8]
// Tile 128x128, BK=64, 4 waves. Flat grid 768 with bijective XCD swizzle.
// ---------------------------------------------------------------------------
__global__ __launch_bounds__(256) void gemm_qkv(
    const u16* __restrict__ A, const u16* __restrict__ BT,
    const float* __restrict__ bq, const float* __restrict__ bk,
    const float* __restrict__ bv, u16* __restrict__ qk,
    u16* __restrict__ v3, float qscale)
{
    __shared__ __align__(16) u16 As[128 * 64];
    __shared__ __align__(16) u16 Bs[128 * 64];
    const int tid = threadIdx.x, lane = tid & 63, w = tid >> 6;
    const int l15 = lane & 15, l4 = lane >> 4;

    const int bidf = blockIdx.x;
    const int xcd = bidf & 7, pos = bidf >> 3;
    const int swz = xcd * 96 + pos;
    const int by = swz / 12, bx = swz - by * 12;
    const int tm = by * 128, tn = bx * 128;
    const int wm = (w >> 1) * 64, wn = (w & 1) * 64;

    f32x4 acc[4][4] = {};

    for (int k0 = 0; k0 < 512; k0 += 64) {
#pragma unroll
        for (int i = 0; i < 4; ++i) {
            int call = w * 4 + i;
            int c = call * 64 + lane;
            int r = c >> 3, j = c & 7;
            async_cp16(A + (size_t)(tm + r) * 512 + k0 + ((j ^ (r & 7)) << 3),
                       &As[call * 512]);
            async_cp16(BT + (size_t)(tn + r) * 512 + k0 + ((j ^ (r & 7)) << 3),
                       &Bs[call * 512]);
        }
        __syncthreads();
#pragma unroll
        for (int ks = 0; ks < 2; ++ks) {
            bf16x8 af[4], bf[4];
#pragma unroll
            for (int mf = 0; mf < 4; ++mf) {
                int r = wm + mf * 16 + l15;
                int j = ks * 4 + l4;
                af[mf] = *reinterpret_cast<const bf16x8*>(&As[(r * 8 + (j ^ (r & 7))) * 8]);
            }
#pragma unroll
            for (int nf = 0; nf < 4; ++nf) {
                int r = wn + nf * 16 + l15;
                int j = ks * 4 + l4;
                bf[nf] = *reinterpret_cast<const bf16x8*>(&Bs[(r * 8 + (j ^ (r & 7))) * 8]);
            }
#pragma unroll
            for (int mf = 0; mf < 4; ++mf)
#pragma unroll
                for (int nf = 0; nf < 4; ++nf)
                    acc[mf][nf] = __builtin_amdgcn_mfma_f32_16x16x32_bf16(
                        af[mf], bf[nf], acc[mf][nf], 0, 0, 0);
        }
        __syncthreads();
    }
    // epilogue: C/D col=lane&15, row=(lane>>4)*4+reg
#pragma unroll
    for (int nf = 0; nf < 4; ++nf) {
        const int col = tn + wn + nf * 16 + l15;
        if (col < QKN) {
            const float bias_v = (col < 512) ? bq[col] : bk[col - 512];
            const float scl = (col < 512) ? qscale : 1.0f;
#pragma unroll
            for (int mf = 0; mf < 4; ++mf)
#pragma unroll
                for (int r = 0; r < 4; ++r) {
                    int row = tm + wm + mf * 16 + l4 * 4 + r;
                    qk[(size_t)row * QKN + col] = f2bf((acc[mf][nf][r] + bias_v) * scl);
                }
        } else {
            const int dcol = col - QKN;                  // 0..511
            const float bias_v = bv[dcol];
            const int hh = dcol >> 6, d64 = dcol & 63;
            const int n = d64 >> 4, dd = d64 & 15;
#pragma unroll
            for (int mf = 0; mf < 4; ++mf) {
                int row0 = tm + wm + mf * 16 + l4 * 4;
                int b = row0 >> 11, s = row0 & 2047;
                int t = s >> 6, s6 = s & 63;
                int ks = s6 >> 5, l4i = (s6 >> 3) & 3, kvi = s6 & 7;
                ushort4 pk;
                pk.x = f2bf(acc[mf][nf][0] + bias_v);
                pk.y = f2bf(acc[mf][nf][1] + bias_v);
                pk.z = f2bf(acc[mf][nf][2] + bias_v);
                pk.w = f2bf(acc[mf][nf][3] + bias_v);
                size_t idx = (((((size_t)(b * 8 + hh) * 32 + t) * 4 + n) * 2 + ks) * 4
                              + l4i) * 128 + dd * 8 + kvi;
                *reinterpret_cast<ushort4*>(&v3[idx]) = pk;
            }
        }
    }
}

// ---------------------------------------------------------------------------
// Flash attention v16 = v15 kv-split x2, with the register bound FIXED:
// __launch_bounds__(256,6) caps VGPR at ~85 (vs body need ~56-60) so the
// allocator does NOT spill (v15's (256,8) forced VGPR 32 -> ~1GB scratch
// traffic). At alloc <=64 the HW can still co-schedule 8 blocks/CU from
// grid 2048. Inner structure: v13 (pi-permuted K staging 16KB dbuf,
// swapped QK^T, register P, ones-MFMA l, V from re-blocked v3 in L2);
// each block does 16 kv tiles, writes unnormalized O (bf16) + l (f32).
// ---------------------------------------------------------------------------
__global__ __launch_bounds__(256, 6) void flash_mfma(
    const u16* __restrict__ qk, const u16* __restrict__ v3,
    const float* __restrict__ pw_ptr, u16* __restrict__ opart,
    float* __restrict__ lpart)
{
    __shared__ __align__(16) u16 Kb[2][4096];   // [64 rho][64 dh], chunk-swz

    const int tid = threadIdx.x, lane = tid & 63, w = tid >> 6;
    const int l15 = lane & 15, l4 = lane >> 4;
    const int bid = blockIdx.x;
    const int x = bid & 7, g = bid >> 3;          // g in [0,256)
    const int bh = x * 4 + (g >> 6);              // XCD x owns bh 4x..4x+3
    const int rem = g & 63, qt = rem >> 1, half = rem & 1;
    const int h = bh & 7, b = bh >> 3;
    const float pwl = pw_ptr[0] * LOG2E;

    const u16* qbase = qk + (size_t)b * S_ * QKN + h * 64;
    const u16* kbase = qbase + 512;
    const u16* vbase = v3 + (size_t)bh * 32 * 4 * 2 * 512 + l4 * 128 + l15 * 8;

    const int qrow0 = qt * 64 + w * 16;   // wave's first q row
    bf16x8 qb[2];
#pragma unroll
    for (int ks2 = 0; ks2 < 2; ++ks2)
        qb[ks2] = *reinterpret_cast<const bf16x8*>(
            &qbase[(size_t)(qrow0 + l15) * QKN + ks2 * 32 + l4 * 8]);

    const bf16x8 ones = {(short)0x3F80, (short)0x3F80, (short)0x3F80, (short)0x3F80,
                         (short)0x3F80, (short)0x3F80, (short)0x3F80, (short)0x3F80};

    f32x4 accv[4] = {};
    f32x4 accl = {};
    const int t0 = half * 16;

#define STAGE(buf, jj) do {                                                        \
    _Pragma("unroll")                                                              \
    for (int i_ = 0; i_ < 2; ++i_) {                                               \
        int call_ = w * 2 + i_;                                                    \
        int c_ = call_ * 64 + lane;                                                \
        int rho_ = c_ >> 3, j_ = c_ & 7;                                           \
        int pi_ = (rho_ & 32) | ((rho_ & 12) << 1) | ((rho_ & 16) >> 2)            \
                | (rho_ & 3);                                                      \
        async_cp16(kbase + (size_t)((jj) + pi_) * QKN + ((j_ ^ (rho_ & 7)) << 3),  \
                   &Kb[buf][call_ * 512]);                                         \
    } } while (0)

    STAGE(0, t0 << 6);
    __syncthreads();
    int cur = 0;

    for (int ti = 0; ti < 16; ++ti) {
        const int t = t0 + ti;
        const int j0 = t << 6;
        const u16* vt = vbase + (size_t)t * 4096;

        // ---- V B-frags n=0,1 early (contiguous 1KB loads from L2) ----
        bf16x8 vb01[2][2];
#pragma unroll
        for (int n = 0; n < 2; ++n)
#pragma unroll
            for (int ks = 0; ks < 2; ++ks)
                vb01[n][ks] = *reinterpret_cast<const bf16x8*>(
                    vt + (n * 2 + ks) * 512);

        if (ti < 15) STAGE(cur ^ 1, (t + 1) << 6);

        // ---- swapped QK^T: S^T[rho][q], A = K(permuted) LDS, B = Q regs ----
        f32x4 s[4] = {};
        __builtin_amdgcn_s_setprio(1);
#pragma unroll
        for (int c = 0; c < 4; ++c)
#pragma unroll
            for (int ks2 = 0; ks2 < 2; ++ks2) {
                const int rr = c * 16 + l15;
                const int sl = ks2 * 4 + l4;
                bf16x8 ka = *reinterpret_cast<const bf16x8*>(
                    &Kb[cur][(rr * 8 + (sl ^ (rr & 7))) * 8]);
                s[c] = __builtin_amdgcn_mfma_f32_16x16x32_bf16(ka, qb[ks2], s[c], 0, 0, 0);
            }
        __builtin_amdgcn_s_setprio(0);

        // ---- V B-frags n=2,3 ----
        bf16x8 vb23[2][2];
#pragma unroll
        for (int n = 0; n < 2; ++n)
#pragma unroll
            for (int ks = 0; ks < 2; ++ks)
                vb23[n][ks] = *reinterpret_cast<const bf16x8*>(
                    vt + ((n + 2) * 2 + ks) * 512);

        // ---- diagonal prior: kv = (c>>1)*32 + l4*8 + (c&1)*4 + r ----
        if (t == qt) {
#pragma unroll
            for (int c = 0; c < 4; ++c)
#pragma unroll
                for (int r = 0; r < 4; ++r) {
                    int kv = (c >> 1) * 32 + l4 * 8 + (c & 1) * 4 + r;
                    if (j0 + kv == qrow0 + l15) s[c][r] += pwl;
                }
        }

        // ---- P = 2^s -> PV A-fragments (pure registers) ----
        bf16x8 pa[2];
#pragma unroll
        for (int ks = 0; ks < 2; ++ks)
#pragma unroll
            for (int d2 = 0; d2 < 2; ++d2)
#pragma unroll
                for (int r = 0; r < 4; ++r)
                    pa[ks][d2 * 4 + r] = (short)f2bf(exp2f(s[ks * 2 + d2][r]));

        // ---- PV + ones-row-sum ----
        __builtin_amdgcn_s_setprio(1);
        accl = __builtin_amdgcn_mfma_f32_16x16x32_bf16(pa[0], ones, accl, 0, 0, 0);
        accl = __builtin_amdgcn_mfma_f32_16x16x32_bf16(pa[1], ones, accl, 0, 0, 0);
#pragma unroll
        for (int n = 0; n < 2; ++n)
#pragma unroll
            for (int ks = 0; ks < 2; ++ks)
                accv[n] = __builtin_amdgcn_mfma_f32_16x16x32_bf16(
                    pa[ks], vb01[n][ks], accv[n], 0, 0, 0);
#pragma unroll
        for (int n = 0; n < 2; ++n)
#pragma unroll
            for (int ks = 0; ks < 2; ++ks)
                accv[n + 2] = __builtin_amdgcn_mfma_f32_16x16x32_bf16(
                    pa[ks], vb23[n][ks], accv[n + 2], 0, 0, 0);
        __builtin_amdgcn_s_setprio(0);

        __syncthreads();
        cur ^= 1;
    }
#undef STAGE

    // ---- epilogue: write unnormalized partials ----
    const size_t cell = (size_t)(bh * 32 + qt) * 2 + half;
#pragma unroll
    for (int r = 0; r < 4; ++r) {
        const int row6 = w * 16 + l4 * 4 + r;
#pragma unroll
        for (int nf = 0; nf < 4; ++nf)
            opart[cell * 4096 + (size_t)row6 * 64 + nf * 16 + l15] =
                f2bf(accv[nf][r]);
        if (l15 == 0) lpart[cell * 64 + row6] = accl[r];
    }
}

// ---------------------------------------------------------------------------
// Combine: att = (O0 + O1) / (l0 + l1).  Grid 1024 (bh*32+qt), 256 thr.
// ---------------------------------------------------------------------------
__global__ __launch_bounds__(256) void combine(
    const u16* __restrict__ opart, const float* __restrict__ lpart,
    u16* __restrict__ att)
{
    const int cp = blockIdx.x;            // bh*32 + qt
    const int bh = cp >> 5, qt = cp & 31;
    const int h = bh & 7, b = bh >> 3;
    const int tid = threadIdx.x;
    const int row = tid >> 2, cg = tid & 3;

    const float inv = 1.0f / (lpart[(size_t)cp * 128 + row] +
                              lpart[(size_t)cp * 128 + 64 + row]);
    const u16* p0 = opart + (size_t)cp * 8192 + (size_t)row * 64 + cg * 16;
    const u16* p1 = p0 + 4096;

    u16* dst = att + ((size_t)(b * S_ + qt * 64 + row)) * HD_ + h * 64 + cg * 16;
#pragma unroll
    for (int hchunk = 0; hchunk < 2; ++hchunk) {
        bf16x8 a = *reinterpret_cast<const bf16x8*>(p0 + hchunk * 8);
        bf16x8 c = *reinterpret_cast<const bf16x8*>(p1 + hchunk * 8);
        bf16x8 o;
#pragma unroll
        for (int e = 0; e < 8; ++e)
            o[e] = (short)f2bf((bf2f((u16)a[e]) + bf2f((u16)c[e])) * inv);
        *reinterpret_cast<bf16x8*>(dst + hchunk * 8) = o;
    }
}

// ---------------------------------------------------------------------------
// Output projection v2: out[M,64] = att[M,512] @ WoT[64,512]^T + bo.
// 32 rows/block, 4 waves: (row-group w&1) x (K-half w>>1); f32 partials
// reduced through LDS. Grid 256.
// ---------------------------------------------------------------------------
__global__ __launch_bounds__(256) void out_proj(
    const u16* __restrict__ att, const u16* __restrict__ WoT,
    const float* __restrict__ bo, float* __restrict__ out)
{
    __shared__ float red[32][65];
    const int tid = threadIdx.x, lane = tid & 63, w = tid >> 6;
    const int l15 = lane & 15, l4 = lane >> 4;
    const int row0 = blockIdx.x * 32;
    const int rsub = (w & 1) * 16, kh = w >> 1;

    f32x4 acc[4] = {};
#pragma unroll
    for (int ks = 0; ks < 8; ++ks) {
        bf16x8 a = *reinterpret_cast<const bf16x8*>(
            &att[(size_t)(row0 + rsub + l15) * 512 + (kh * 8 + ks) * 32 + l4 * 8]);
#pragma unroll
        for (int nf = 0; nf < 4; ++nf) {
            bf16x8 bb = *reinterpret_cast<const bf16x8*>(
                &WoT[(size_t)(nf * 16 + l15) * 512 + (kh * 8 + ks) * 32 + l4 * 8]);
            acc[nf] = __builtin_amdgcn_mfma_f32_16x16x32_bf16(a, bb, acc[nf], 0, 0, 0);
        }
    }
    if (kh == 1) {
#pragma unroll
        for (int nf = 0; nf < 4; ++nf)
#pragma unroll
            for (int r = 0; r < 4; ++r)
                red[rsub + l4 * 4 + r][nf * 16 + l15] = acc[nf][r];
    }
    __syncthreads();
    if (kh == 0) {
#pragma unroll
        for (int nf = 0; nf < 4; ++nf) {
            int n = nf * 16 + l15;
            float bias_v = bo[n];
#pragma unroll
            for (int r = 0; r < 4; ++r)
                out[(size_t)(row0 + rsub + l4 * 4 + r) * 64 + n] =
                    acc[nf][r] + red[rsub + l4 * 4 + r][n] + bias_v;
        }
    }
}

// ---------------------------------------------------------------------------
extern "C" void kernel_launch(void* const* d_in, const int* in_sizes, int n_in,
                              void* d_out, int out_size, void* d_ws, size_t ws_size,
                              hipStream_t stream)
{
    const float* x  = (const float*)d_in[0];
    const float* Wq = (const float*)d_in[2];
    const float* bq = (const float*)d_in[3];
    const float* Wk = (const float*)d_in[4];
    const float* bk = (const float*)d_in[5];
    const float* Wv = (const float*)d_in[6];
    const float* bv = (const float*)d_in[7];
    const float* Wo = (const float*)d_in[8];
    const float* bo = (const float*)d_in[9];
    const float* pw = (const float*)d_in[10];

    u16* ws = (u16*)d_ws;
    size_t o = 0;
    u16* xb    = ws + o; o += (size_t)M_ * D_;           // 8 MB
    u16* WqkvT = ws + o; o += (size_t)QKVN * D_;         // 1.5 MB
    u16* WoT   = ws + o; o += (size_t)DH_ * HD_;
    u16* qkb   = ws + o; o += (size_t)M_ * QKN;          // 16 MB
    u16* v3b   = ws + o; o += (size_t)M_ * HD_;          // 8 MB
    u16* att   = ws + o; o += (size_t)M_ * HD_;          // 8 MB
    u16* opart = ws + o; o += (size_t)2048 * 4096;       // 16 MB (bf16)
    float* lprt = (float*)(ws + o); o += (size_t)2048 * 64 * 2;  // 512 KB

    dim3 blk(256);
    prep_all<<<dim3(64, 8, 5), blk, 0, stream>>>(x, Wq, Wk, Wv, Wo, xb, WqkvT, WoT);

    gemm_qkv<<<dim3(768), blk, 0, stream>>>(
        xb, WqkvT, bq, bk, bv, qkb, v3b, 0.125f * LOG2E);

    flash_mfma<<<dim3(2048), blk, 0, stream>>>(qkb, v3b, pw, opart, lprt);

    combine<<<dim3(1024), blk, 0, stream>>>(opart, lprt, att);

    out_proj<<<dim3(256), blk, 0, stream>>>(att, WoT, bo, (float*)d_out);
}

// Round 17
// 98.772 us; speedup vs baseline: 3.7099x; 2.1643x over previous
//
#include <hip/hip_runtime.h>
#include <hip/hip_bf16.h>

#define B_ 4
#define S_ 2048
#define D_ 512
#define H_ 8
#define DH_ 64
#define HD_ 512
#define M_ 8192
#define QKVN 1536
#define QKN 1024
#define LOG2E 1.4426950408889634f

typedef __attribute__((ext_vector_type(8))) short bf16x8;
typedef __attribute__((ext_vector_type(4))) float f32x4;
typedef unsigned short u16;

__device__ inline u16 f2bf(float f) {
    __hip_bfloat16 h = __float2bfloat16(f);
    return *reinterpret_cast<u16*>(&h);
}

__device__ inline void async_cp16(const void* g, void* l) {
    __builtin_amdgcn_global_load_lds(
        (const __attribute__((address_space(1))) unsigned int*)g,
        (__attribute__((address_space(3))) unsigned int*)l, 16, 0, 0);
}

// ---------------------------------------------------------------------------
// Combined prep: z<3 -> transpose Wq/Wk/Wv (512x512 f32) into WqkvT bf16;
// z==3 -> transpose Wo (512x64) into WoT; z==4 -> cast x f32->bf16.
// Grid (64, 8, 5).
// ---------------------------------------------------------------------------
__global__ __launch_bounds__(256) void prep_all(
    const float* __restrict__ x, const float* __restrict__ Wq,
    const float* __restrict__ Wk, const float* __restrict__ Wv,
    const float* __restrict__ Wo, u16* __restrict__ xb,
    u16* __restrict__ WqkvT, u16* __restrict__ WoT)
{
    const int z = blockIdx.z;
    const int tid = threadIdx.x;

    if (z == 4) {            // ---- cast x -> bf16, 4 chunks per thread ----
        const int id = blockIdx.y * 64 + blockIdx.x;     // 0..511
#pragma unroll
        for (int it = 0; it < 4; ++it) {
            int i = it * 131072 + id * 256 + tid;        // n8 = 524288
            float4 a = *reinterpret_cast<const float4*>(&x[(size_t)i * 8]);
            float4 b = *reinterpret_cast<const float4*>(&x[(size_t)i * 8 + 4]);
            bf16x8 o;
            o[0] = f2bf(a.x); o[1] = f2bf(a.y); o[2] = f2bf(a.z); o[3] = f2bf(a.w);
            o[4] = f2bf(b.x); o[5] = f2bf(b.y); o[6] = f2bf(b.z); o[7] = f2bf(b.w);
            *reinterpret_cast<bf16x8*>(&xb[(size_t)i * 8]) = o;
        }
        return;
    }

    const float* src; u16* dst; int R, C;
    if (z < 3) { if (blockIdx.x >= 8) return;
                 src = (z == 0) ? Wq : (z == 1) ? Wk : Wv;
                 dst = WqkvT + (size_t)z * 512 * 512; R = 512; C = 512; }
    else       { if (blockIdx.x) return; src = Wo; dst = WoT; R = 512; C = 64; }

    __shared__ u16 T[64][65];
    const int c0 = blockIdx.x * 64, r0 = blockIdx.y * 64;
#pragma unroll
    for (int i = 0; i < 4; ++i) {
        int idx = i * 256 + tid;
        int r = idx >> 4, q4 = (idx & 15) << 2;
        float4 vv = *reinterpret_cast<const float4*>(&src[(size_t)(r0 + r) * C + c0 + q4]);
        T[r][q4 + 0] = f2bf(vv.x); T[r][q4 + 1] = f2bf(vv.y);
        T[r][q4 + 2] = f2bf(vv.z); T[r][q4 + 3] = f2bf(vv.w);
    }
    __syncthreads();
#pragma unroll
    for (int i = 0; i < 2; ++i) {
        int idx = i * 256 + tid;
        int cc = idx >> 3, jj = idx & 7;
        bf16x8 o;
#pragma unroll
        for (int e = 0; e < 8; ++e) o[e] = (short)T[jj * 8 + e][cc];
        *reinterpret_cast<bf16x8*>(&dst[(size_t)(c0 + cc) * R + r0 + jj * 8]) = o;
    }
}

// ---------------------------------------------------------------------------
// Fused QKV GEMM: [M,512] @ [1536,512]^T. Q/K cols -> qk[M][1024] (q scaled
// by 0.125*log2e); V cols -> v3 re-blocked fragment layout:
//   v3[bh][t2 32][n 4][ks 2][l4 4][dd 16][kvi 8]
// Tile 128x128, BK=64, 4 waves. Flat grid 768 with bijective XCD swizzle.
// ---------------------------------------------------------------------------
__global__ __launch_bounds__(256) void gemm_qkv(
    const u16* __restrict__ A, const u16* __restrict__ BT,
    const float* __restrict__ bq, const float* __restrict__ bk,
    const float* __restrict__ bv, u16* __restrict__ qk,
    u16* __restrict__ v3, float qscale)
{
    __shared__ __align__(16) u16 As[128 * 64];
    __shared__ __align__(16) u16 Bs[128 * 64];
    const int tid = threadIdx.x, lane = tid & 63, w = tid >> 6;
    const int l15 = lane & 15, l4 = lane >> 4;

    const int bidf = blockIdx.x;
    const int xcd = bidf & 7, pos = bidf >> 3;
    const int swz = xcd * 96 + pos;
    const int by = swz / 12, bx = swz - by * 12;
    const int tm = by * 128, tn = bx * 128;
    const int wm = (w >> 1) * 64, wn = (w & 1) * 64;

    f32x4 acc[4][4] = {};

    for (int k0 = 0; k0 < 512; k0 += 64) {
#pragma unroll
        for (int i = 0; i < 4; ++i) {
            int call = w * 4 + i;
            int c = call * 64 + lane;
            int r = c >> 3, j = c & 7;
            async_cp16(A + (size_t)(tm + r) * 512 + k0 + ((j ^ (r & 7)) << 3),
                       &As[call * 512]);
            async_cp16(BT + (size_t)(tn + r) * 512 + k0 + ((j ^ (r & 7)) << 3),
                       &Bs[call * 512]);
        }
        __syncthreads();
#pragma unroll
        for (int ks = 0; ks < 2; ++ks) {
            bf16x8 af[4], bf[4];
#pragma unroll
            for (int mf = 0; mf < 4; ++mf) {
                int r = wm + mf * 16 + l15;
                int j = ks * 4 + l4;
                af[mf] = *reinterpret_cast<const bf16x8*>(&As[(r * 8 + (j ^ (r & 7))) * 8]);
            }
#pragma unroll
            for (int nf = 0; nf < 4; ++nf) {
                int r = wn + nf * 16 + l15;
                int j = ks * 4 + l4;
                bf[nf] = *reinterpret_cast<const bf16x8*>(&Bs[(r * 8 + (j ^ (r & 7))) * 8]);
            }
#pragma unroll
            for (int mf = 0; mf < 4; ++mf)
#pragma unroll
                for (int nf = 0; nf < 4; ++nf)
                    acc[mf][nf] = __builtin_amdgcn_mfma_f32_16x16x32_bf16(
                        af[mf], bf[nf], acc[mf][nf], 0, 0, 0);
        }
        __syncthreads();
    }
    // epilogue: C/D col=lane&15, row=(lane>>4)*4+reg
#pragma unroll
    for (int nf = 0; nf < 4; ++nf) {
        const int col = tn + wn + nf * 16 + l15;
        if (col < QKN) {
            const float bias_v = (col < 512) ? bq[col] : bk[col - 512];
            const float scl = (col < 512) ? qscale : 1.0f;
#pragma unroll
            for (int mf = 0; mf < 4; ++mf)
#pragma unroll
                for (int r = 0; r < 4; ++r) {
                    int row = tm + wm + mf * 16 + l4 * 4 + r;
                    qk[(size_t)row * QKN + col] = f2bf((acc[mf][nf][r] + bias_v) * scl);
                }
        } else {
            const int dcol = col - QKN;                  // 0..511
            const float bias_v = bv[dcol];
            const int hh = dcol >> 6, d64 = dcol & 63;
            const int n = d64 >> 4, dd = d64 & 15;
#pragma unroll
            for (int mf = 0; mf < 4; ++mf) {
                int row0 = tm + wm + mf * 16 + l4 * 4;
                int b = row0 >> 11, s = row0 & 2047;
                int t = s >> 6, s6 = s & 63;
                int ks = s6 >> 5, l4i = (s6 >> 3) & 3, kvi = s6 & 7;
                ushort4 pk;
                pk.x = f2bf(acc[mf][nf][0] + bias_v);
                pk.y = f2bf(acc[mf][nf][1] + bias_v);
                pk.z = f2bf(acc[mf][nf][2] + bias_v);
                pk.w = f2bf(acc[mf][nf][3] + bias_v);
                size_t idx = (((((size_t)(b * 8 + hh) * 32 + t) * 4 + n) * 2 + ks) * 4
                              + l4i) * 128 + dd * 8 + kvi;
                *reinterpret_cast<ushort4*>(&v3[idx]) = pk;
            }
        }
    }
}

// ---------------------------------------------------------------------------
// Flash attention v14 (champion): 2 KV-tiles per barrier (16 barriers).
// K staged 128 rho-rows per buffer (pi-permuted within each 64-row half),
// double-buffered (32KB LDS); V from re-blocked v3 in L2 (contiguous 1KB
// fragment loads); swapped QK^T, register-resident P, ones-MFMA row sums.
// 4 waves x 16 q-rows, grid 1024, __launch_bounds__(256,4).
// ---------------------------------------------------------------------------
__global__ __launch_bounds__(256, 4) void flash_mfma(
    const u16* __restrict__ qk, const u16* __restrict__ v3,
    const float* __restrict__ pw_ptr, u16* __restrict__ att)
{
    __shared__ __align__(16) u16 Kb[2][8192];   // [128 rho][64 dh], chunk-swz

    const int tid = threadIdx.x, lane = tid & 63, w = tid >> 6;
    const int l15 = lane & 15, l4 = lane >> 4;
    const int bid = blockIdx.x;
    const int x = bid & 7, g = bid >> 3;
    const int bh = x * 4 + (g >> 5), qt = g & 31;
    const int h = bh & 7, b = bh >> 3;
    const float pwl = pw_ptr[0] * LOG2E;

    const u16* qbase = qk + (size_t)b * S_ * QKN + h * 64;
    const u16* kbase = qbase + 512;
    const u16* vbase = v3 + (size_t)bh * 32 * 4 * 2 * 512 + l4 * 128 + l15 * 8;

    const int qrow0 = qt * 64 + w * 16;   // wave's first q row
    bf16x8 qb[2];
#pragma unroll
    for (int ks2 = 0; ks2 < 2; ++ks2)
        qb[ks2] = *reinterpret_cast<const bf16x8*>(
            &qbase[(size_t)(qrow0 + l15) * QKN + ks2 * 32 + l4 * 8]);

    const bf16x8 ones = {(short)0x3F80, (short)0x3F80, (short)0x3F80, (short)0x3F80,
                         (short)0x3F80, (short)0x3F80, (short)0x3F80, (short)0x3F80};

    f32x4 accv[4] = {};
    f32x4 accl = {};

    // Stage 128 K rows (2 tiles): 16 x 1KB calls, 4 per wave. Rows
    // pi-permuted within each 64-row half; dest linear.
#define STAGE2(buf, jj) do {                                                       \
    _Pragma("unroll")                                                              \
    for (int i_ = 0; i_ < 4; ++i_) {                                               \
        int call_ = w * 4 + i_;                                                    \
        int c_ = call_ * 64 + lane;                                                \
        int rho_ = c_ >> 3, j_ = c_ & 7;                                           \
        int r6_ = rho_ & 63;                                                       \
        int pi_ = (rho_ & 64) | (r6_ & 32) | ((r6_ & 12) << 1)                     \
                | ((r6_ & 16) >> 2) | (r6_ & 3);                                   \
        async_cp16(kbase + (size_t)((jj) + pi_) * QKN + ((j_ ^ (r6_ & 7)) << 3),   \
                   &Kb[buf][call_ * 512]);                                         \
    } } while (0)

    STAGE2(0, 0);
    __syncthreads();
    int cur = 0;

    for (int t = 0; t < 16; ++t) {
        if (t < 15) STAGE2(cur ^ 1, (t + 1) << 7);

#pragma unroll
        for (int half = 0; half < 2; ++half) {
            const int t2 = t * 2 + half;
            const int j0h = t2 << 6;
            const u16* vt = vbase + (size_t)t2 * 4096;
            const u16* kb = &Kb[cur][half * 4096];

            // ---- V B-frags n=0,1 early (contiguous 1KB loads from L2) ----
            bf16x8 vb01[2][2];
#pragma unroll
            for (int n = 0; n < 2; ++n)
#pragma unroll
                for (int ks = 0; ks < 2; ++ks)
                    vb01[n][ks] = *reinterpret_cast<const bf16x8*>(
                        vt + (n * 2 + ks) * 512);

            // ---- swapped QK^T: S^T[rho][q], A = K(permuted), B = Q regs ----
            f32x4 s[4] = {};
            __builtin_amdgcn_s_setprio(1);
#pragma unroll
            for (int c = 0; c < 4; ++c)
#pragma unroll
                for (int ks2 = 0; ks2 < 2; ++ks2) {
                    const int rr = c * 16 + l15;
                    const int sl = ks2 * 4 + l4;
                    bf16x8 ka = *reinterpret_cast<const bf16x8*>(
                        &kb[(rr * 8 + (sl ^ (rr & 7))) * 8]);
                    s[c] = __builtin_amdgcn_mfma_f32_16x16x32_bf16(ka, qb[ks2], s[c], 0, 0, 0);
                }
            __builtin_amdgcn_s_setprio(0);

            // ---- V B-frags n=2,3 ----
            bf16x8 vb23[2][2];
#pragma unroll
            for (int n = 0; n < 2; ++n)
#pragma unroll
                for (int ks = 0; ks < 2; ++ks)
                    vb23[n][ks] = *reinterpret_cast<const bf16x8*>(
                        vt + ((n + 2) * 2 + ks) * 512);

            // ---- diagonal prior: kv = (c>>1)*32 + l4*8 + (c&1)*4 + r ----
            if (t2 == qt) {
#pragma unroll
                for (int c = 0; c < 4; ++c)
#pragma unroll
                    for (int r = 0; r < 4; ++r) {
                        int kv = (c >> 1) * 32 + l4 * 8 + (c & 1) * 4 + r;
                        if (j0h + kv == qrow0 + l15) s[c][r] += pwl;
                    }
            }

            // ---- P = 2^s -> PV A-fragments (pure registers) ----
            bf16x8 pa[2];
#pragma unroll
            for (int ks = 0; ks < 2; ++ks)
#pragma unroll
                for (int d2 = 0; d2 < 2; ++d2)
#pragma unroll
                    for (int r = 0; r < 4; ++r)
                        pa[ks][d2 * 4 + r] = (short)f2bf(exp2f(s[ks * 2 + d2][r]));

            // ---- PV + ones-row-sum ----
            __builtin_amdgcn_s_setprio(1);
            accl = __builtin_amdgcn_mfma_f32_16x16x32_bf16(pa[0], ones, accl, 0, 0, 0);
            accl = __builtin_amdgcn_mfma_f32_16x16x32_bf16(pa[1], ones, accl, 0, 0, 0);
#pragma unroll
            for (int n = 0; n < 2; ++n)
#pragma unroll
                for (int ks = 0; ks < 2; ++ks)
                    accv[n] = __builtin_amdgcn_mfma_f32_16x16x32_bf16(
                        pa[ks], vb01[n][ks], accv[n], 0, 0, 0);
#pragma unroll
            for (int n = 0; n < 2; ++n)
#pragma unroll
                for (int ks = 0; ks < 2; ++ks)
                    accv[n + 2] = __builtin_amdgcn_mfma_f32_16x16x32_bf16(
                        pa[ks], vb23[n][ks], accv[n + 2], 0, 0, 0);
            __builtin_amdgcn_s_setprio(0);
        }

        __syncthreads();
        cur ^= 1;
    }
#undef STAGE2

    // ---- epilogue: accl[r] IS l for q-row qrow0 + l4*4 + r ----
#pragma unroll
    for (int r = 0; r < 4; ++r) {
        float inv = 1.0f / accl[r];
        int row = qrow0 + l4 * 4 + r;
#pragma unroll
        for (int nf = 0; nf < 4; ++nf)
            att[(size_t)(b * S_ + row) * HD_ + h * 64 + nf * 16 + l15] =
                f2bf(accv[nf][r] * inv);
    }
}

// ---------------------------------------------------------------------------
// Output projection v2: out[M,64] = att[M,512] @ WoT[64,512]^T + bo.
// 32 rows/block, 4 waves: (row-group w&1) x (K-half w>>1); f32 partials
// reduced through LDS. Grid 256.
// ---------------------------------------------------------------------------
__global__ __launch_bounds__(256) void out_proj(
    const u16* __restrict__ att, const u16* __restrict__ WoT,
    const float* __restrict__ bo, float* __restrict__ out)
{
    __shared__ float red[32][65];
    const int tid = threadIdx.x, lane = tid & 63, w = tid >> 6;
    const int l15 = lane & 15, l4 = lane >> 4;
    const int row0 = blockIdx.x * 32;
    const int rsub = (w & 1) * 16, kh = w >> 1;

    f32x4 acc[4] = {};
#pragma unroll
    for (int ks = 0; ks < 8; ++ks) {
        bf16x8 a = *reinterpret_cast<const bf16x8*>(
            &att[(size_t)(row0 + rsub + l15) * 512 + (kh * 8 + ks) * 32 + l4 * 8]);
#pragma unroll
        for (int nf = 0; nf < 4; ++nf) {
            bf16x8 bb = *reinterpret_cast<const bf16x8*>(
                &WoT[(size_t)(nf * 16 + l15) * 512 + (kh * 8 + ks) * 32 + l4 * 8]);
            acc[nf] = __builtin_amdgcn_mfma_f32_16x16x32_bf16(a, bb, acc[nf], 0, 0, 0);
        }
    }
    if (kh == 1) {
#pragma unroll
        for (int nf = 0; nf < 4; ++nf)
#pragma unroll
            for (int r = 0; r < 4; ++r)
                red[rsub + l4 * 4 + r][nf * 16 + l15] = acc[nf][r];
    }
    __syncthreads();
    if (kh == 0) {
#pragma unroll
        for (int nf = 0; nf < 4; ++nf) {
            int n = nf * 16 + l15;
            float bias_v = bo[n];
#pragma unroll
            for (int r = 0; r < 4; ++r)
                out[(size_t)(row0 + rsub + l4 * 4 + r) * 64 + n] =
                    acc[nf][r] + red[rsub + l4 * 4 + r][n] + bias_v;
        }
    }
}

// ---------------------------------------------------------------------------
extern "C" void kernel_launch(void* const* d_in, const int* in_sizes, int n_in,
                              void* d_out, int out_size, void* d_ws, size_t ws_size,
                              hipStream_t stream)
{
    const float* x  = (const float*)d_in[0];
    const float* Wq = (const float*)d_in[2];
    const float* bq = (const float*)d_in[3];
    const float* Wk = (const float*)d_in[4];
    const float* bk = (const float*)d_in[5];
    const float* Wv = (const float*)d_in[6];
    const float* bv = (const float*)d_in[7];
    const float* Wo = (const float*)d_in[8];
    const float* bo = (const float*)d_in[9];
    const float* pw = (const float*)d_in[10];

    u16* ws = (u16*)d_ws;
    size_t o = 0;
    u16* xb    = ws + o; o += (size_t)M_ * D_;        // 8 MB
    u16* WqkvT = ws + o; o += (size_t)QKVN * D_;      // 1.5 MB
    u16* WoT   = ws + o; o += (size_t)DH_ * HD_;
    u16* qkb   = ws + o; o += (size_t)M_ * QKN;       // 16 MB
    u16* v3b   = ws + o; o += (size_t)M_ * HD_;       // 8 MB (re-blocked V)
    u16* att   = ws + o; o += (size_t)M_ * HD_;       // 8 MB

    dim3 blk(256);
    prep_all<<<dim3(64, 8, 5), blk, 0, stream>>>(x, Wq, Wk, Wv, Wo, xb, WqkvT, WoT);

    gemm_qkv<<<dim3(768), blk, 0, stream>>>(
        xb, WqkvT, bq, bk, bv, qkb, v3b, 0.125f * LOG2E);

    flash_mfma<<<dim3(1024), blk, 0, stream>>>(qkb, v3b, pw, att);

    out_proj<<<dim3(256), blk, 0, stream>>>(att, WoT, bo, (float*)d_out);
}